// Round 15
// baseline (100.610 us; speedup 1.0000x reference)
//
#include <hip/hip_runtime.h>
#include <math.h>

#define B_ 4
#define N_ 64
#define L_ 128
#define H_ 8
#define E_ 32
#define SC_ 8

typedef __attribute__((ext_vector_type(8))) short short8;
typedef __attribute__((ext_vector_type(4))) float f32x4;
typedef __attribute__((ext_vector_type(4))) _Float16 f16x4;

__device__ __forceinline__ unsigned short f2bf(float x) {
    union { float f; unsigned u; } c; c.f = x;
    unsigned r = (c.u + 0x7fffu + ((c.u >> 16) & 1u)) >> 16;
    return (unsigned short)r;
}
__device__ __forceinline__ float bf2f(unsigned short h) {
    union { unsigned u; float f; } c; c.u = ((unsigned)h) << 16;
    return c.f;
}

// qm[b][h][e][t] = mean over n of queries[b,n,t,h,e] (fp64, float4 + LDS reduce).
// Blocks 0..15 also transpose w/b into the f16 table.
__global__ __launch_bounds__(256) void k_qmean(const float* __restrict__ q,
                                               float* __restrict__ qm,
                                               const float* __restrict__ w,
                                               const float* __restrict__ bias,
                                               _Float16* __restrict__ wTh,
                                               _Float16* __restrict__ bTh) {
    int blk = blockIdx.x;               // b*128 + t
    int b = blk >> 7, t = blk & 127;
    int tid = threadIdx.x;
    int c4 = tid & 63;
    int nq = tid >> 6;
    __shared__ double red[4][256];
    const f32x4* p = (const f32x4*)(q + (((size_t)(b * N_)) * L_ + t) * 256);
    double s0 = 0, s1 = 0, s2 = 0, s3 = 0;
    #pragma unroll 4
    for (int n = nq * 16; n < nq * 16 + 16; ++n) {
        f32x4 v = p[(size_t)n * 8192 + c4];
        s0 += (double)v.x; s1 += (double)v.y; s2 += (double)v.z; s3 += (double)v.w;
    }
    red[nq][c4 * 4 + 0] = s0;
    red[nq][c4 * 4 + 1] = s1;
    red[nq][c4 * 4 + 2] = s2;
    red[nq][c4 * 4 + 3] = s3;
    __syncthreads();
    int c = tid;
    double s = red[0][c] + red[1][c] + red[2][c] + red[3][c];
    qm[((size_t)b * 256 + c) * L_ + t] = (float)(s * (1.0 / 64.0));

    if (blk < 16) {
        int k = blk * 256 + tid;        // 4096 = lp*32+e
        int e = k & 31, lp = k >> 5;
        int cc = e * L_ + lp;
        wTh[k]        = (_Float16)w[cc * 3 + 0];
        wTh[4096 + k] = (_Float16)w[cc * 3 + 1];
        wTh[8192 + k] = (_Float16)w[cc * 3 + 2];
        bTh[k]        = (_Float16)bias[cc];
    }
}

// MFMA corr: part[sc][b][n][h][tau] = sum_{s in chunk, e} keys[b,n,s,h,e]*qm[b,h,e,(s+tau)%128]
__global__ __launch_bounds__(512) void k_corr(const float* __restrict__ keys,
                                              const float* __restrict__ qm,
                                              float* __restrict__ part) {
    int blk = blockIdx.x;
    int sc = blk & 7; int bh = blk >> 3; int h = bh & 7; int b = bh >> 3;
    __shared__ unsigned short Ahi[4][64][40];
    __shared__ unsigned short Alo[4][64][40];
    __shared__ unsigned short Qhi[128][40];
    __shared__ unsigned short Qlo[128][40];
    int tid = threadIdx.x;
    int lane = tid & 63, w = tid >> 6;
    int mg = w & 1, ng = w >> 1;

    {
        int e = tid >> 4; int tq = (tid & 15) * 4;
        const float* qp = qm + ((size_t)b * 256 + h * 32 + e) * 128;
        #pragma unroll
        for (int hf = 0; hf < 2; ++hf) {
            int t0 = tq + hf * 64;
            float4 v = *(const float4*)(qp + t0);
            float vv[4] = {v.x, v.y, v.z, v.w};
            #pragma unroll
            for (int j = 0; j < 4; ++j) {
                unsigned short hi = f2bf(vv[j]);
                Qhi[t0 + j][e] = hi;
                Qlo[t0 + j][e] = f2bf(vv[j] - bf2f(hi));
            }
        }
    }
    int sn = tid >> 3; int se = (tid & 7) * 4;
    const float* kbase = keys + ((size_t)(b * N_ + sn) * L_) * 256 + h * 32 + se;
    #pragma unroll
    for (int p = 0; p < 2; ++p) {
        float4 v = *(const float4*)(kbase + (size_t)(sc * 16 + p) * 256);
        float vv[4] = {v.x, v.y, v.z, v.w};
        ushort4 h4, l4;
        unsigned short* hp = (unsigned short*)&h4;
        unsigned short* lp = (unsigned short*)&l4;
        #pragma unroll
        for (int j = 0; j < 4; ++j) {
            hp[j] = f2bf(vv[j]);
            lp[j] = f2bf(vv[j] - bf2f(hp[j]));
        }
        *(ushort4*)&Ahi[p][sn][se] = h4;
        *(ushort4*)&Alo[p][sn][se] = l4;
    }
    __syncthreads();

    f32x4 acc[2][2];
    #pragma unroll
    for (int i = 0; i < 2; ++i)
        #pragma unroll
        for (int j = 0; j < 2; ++j)
            acc[i][j] = (f32x4){0.f, 0.f, 0.f, 0.f};

    int eb = (lane >> 4) * 8;
    int rA0 = (mg * 2) * 16 + (lane & 15);
    int rA1 = rA0 + 16;
    int tau0 = (ng * 2) * 16 + (lane & 15);
    int tau1 = tau0 + 16;

    for (int it = 0; it < 8; ++it) {
        float4 stg0, stg1;
        if (it < 7) {
            stg0 = *(const float4*)(kbase + (size_t)(sc * 16 + 2 * it + 2) * 256);
            stg1 = *(const float4*)(kbase + (size_t)(sc * 16 + 2 * it + 3) * 256);
        }
        #pragma unroll
        for (int sp = 0; sp < 2; ++sp) {
            int p = 2 * it + sp;
            int slot = p & 3;
            int s = sc * 16 + p;
            short8 ah0 = *(const short8*)&Ahi[slot][rA0][eb];
            short8 ah1 = *(const short8*)&Ahi[slot][rA1][eb];
            short8 al0 = *(const short8*)&Alo[slot][rA0][eb];
            short8 al1 = *(const short8*)&Alo[slot][rA1][eb];
            int t0 = (s + tau0) & 127;
            int t1 = (s + tau1) & 127;
            short8 bh0 = *(const short8*)&Qhi[t0][eb];
            short8 bh1 = *(const short8*)&Qhi[t1][eb];
            short8 bl0 = *(const short8*)&Qlo[t0][eb];
            short8 bl1 = *(const short8*)&Qlo[t1][eb];
            acc[0][0] = __builtin_amdgcn_mfma_f32_16x16x32_bf16(ah0, bh0, acc[0][0], 0, 0, 0);
            acc[0][1] = __builtin_amdgcn_mfma_f32_16x16x32_bf16(ah0, bh1, acc[0][1], 0, 0, 0);
            acc[1][0] = __builtin_amdgcn_mfma_f32_16x16x32_bf16(ah1, bh0, acc[1][0], 0, 0, 0);
            acc[1][1] = __builtin_amdgcn_mfma_f32_16x16x32_bf16(ah1, bh1, acc[1][1], 0, 0, 0);
            acc[0][0] = __builtin_amdgcn_mfma_f32_16x16x32_bf16(ah0, bl0, acc[0][0], 0, 0, 0);
            acc[0][1] = __builtin_amdgcn_mfma_f32_16x16x32_bf16(ah0, bl1, acc[0][1], 0, 0, 0);
            acc[1][0] = __builtin_amdgcn_mfma_f32_16x16x32_bf16(ah1, bl0, acc[1][0], 0, 0, 0);
            acc[1][1] = __builtin_amdgcn_mfma_f32_16x16x32_bf16(ah1, bl1, acc[1][1], 0, 0, 0);
            acc[0][0] = __builtin_amdgcn_mfma_f32_16x16x32_bf16(al0, bh0, acc[0][0], 0, 0, 0);
            acc[0][1] = __builtin_amdgcn_mfma_f32_16x16x32_bf16(al0, bh1, acc[0][1], 0, 0, 0);
            acc[1][0] = __builtin_amdgcn_mfma_f32_16x16x32_bf16(al1, bh0, acc[1][0], 0, 0, 0);
            acc[1][1] = __builtin_amdgcn_mfma_f32_16x16x32_bf16(al1, bh1, acc[1][1], 0, 0, 0);
        }
        if (it < 7) {
            #pragma unroll
            for (int sp = 0; sp < 2; ++sp) {
                int p = 2 * it + 2 + sp;
                int slot = p & 3;
                float4 v = sp ? stg1 : stg0;
                float vv[4] = {v.x, v.y, v.z, v.w};
                ushort4 h4, l4;
                unsigned short* hp = (unsigned short*)&h4;
                unsigned short* lp = (unsigned short*)&l4;
                #pragma unroll
                for (int j = 0; j < 4; ++j) {
                    hp[j] = f2bf(vv[j]);
                    lp[j] = f2bf(vv[j] - bf2f(hp[j]));
                }
                *(ushort4*)&Ahi[slot][sn][se] = h4;
                *(ushort4*)&Alo[slot][sn][se] = l4;
            }
        }
        __syncthreads();
    }

    #pragma unroll
    for (int i = 0; i < 2; ++i) {
        int mt = mg * 2 + i;
        #pragma unroll
        for (int j = 0; j < 2; ++j) {
            int nt = ng * 2 + j;
            int tau = nt * 16 + (lane & 15);
            #pragma unroll
            for (int r = 0; r < 4; ++r) {
                int n = mt * 16 + (lane >> 4) * 4 + r;
                part[((((size_t)sc * B_ + b) * N_ + n) * H_ + h) * L_ + tau] = acc[i][j][r];
            }
        }
    }
}

// top-2 over tau per (b,n,h) with INLINE exact fp64 recompute of near-tie rows.
// 512 blocks x 256 thr; wave w owns row blk=bid*4+w. flagL is block-uniform in
// LDS so the recompute loop is uniform; only ~2 of 512 blocks do extra work.
__global__ __launch_bounds__(256) void k_topk(const float* __restrict__ part,
                                              const float* __restrict__ keys,
                                              const float* __restrict__ qm,
                                              int* __restrict__ didx,
                                              float* __restrict__ sig) {
    int bid = blockIdx.x;
    int tid = threadIdx.x;
    int w = tid >> 6, lane = tid & 63;
    __shared__ float ks_t[L_][E_];      // 16 KB (flagged rows only)
    __shared__ float qs_t[L_][E_];      // 16 KB, swizzled by t&7
    __shared__ double vvL[2][L_];       // 2 KB
    __shared__ int   dA[4][2];
    __shared__ float sA[4][2];
    __shared__ int   flagL[4];

    // ---- Phase A: top-2 + near-tie flag (one row per wave)
    {
        int blk = bid * 4 + w;          // (b*64+n)*8+h
        size_t rb = (size_t)blk * L_;
        const size_t stride = (size_t)B_ * N_ * H_ * L_;
        double s0 = 0.0, s1 = 0.0;
        for (int sc = 0; sc < SC_; ++sc) {
            s0 += (double)part[sc * stride + rb + lane];
            s1 += (double)part[sc * stride + rb + lane + 64];
        }
        float v0 = (float)(s0 * (1.0 / 32.0));
        float v1 = (float)(s1 * (1.0 / 32.0));

        float bv = v0; int bi = lane;
        if (v1 > v0) { bv = v1; bi = lane + 64; }
        #pragma unroll
        for (int m = 32; m; m >>= 1) {
            float ov = __shfl_xor(bv, m, 64);
            int   oi = __shfl_xor(bi, m, 64);
            if (ov > bv || (ov == bv && oi < bi)) { bv = ov; bi = oi; }
        }
        int i1 = bi; float w1v = bv;

        float c0 = (lane == i1) ? -INFINITY : v0;
        float c1 = (lane + 64 == i1) ? -INFINITY : v1;
        float bv2 = c0; int bi2 = lane;
        if (c1 > c0) { bv2 = c1; bi2 = lane + 64; }
        #pragma unroll
        for (int m = 32; m; m >>= 1) {
            float ov = __shfl_xor(bv2, m, 64);
            int   oi = __shfl_xor(bi2, m, 64);
            if (ov > bv2 || (ov == bv2 && oi < bi2)) { bv2 = ov; bi2 = oi; }
        }
        int i2 = bi2; float w2v = bv2;

        float d0 = (lane == i1 || lane == i2) ? -INFINITY : v0;
        float d1 = (lane + 64 == i1 || lane + 64 == i2) ? -INFINITY : v1;
        float bv3 = fmaxf(d0, d1);
        #pragma unroll
        for (int m = 32; m; m >>= 1) bv3 = fmaxf(bv3, __shfl_xor(bv3, m, 64));

        if (lane == 0) {
            dA[w][0] = i1; dA[w][1] = i2;
            sA[w][0] = 1.f / (1.f + expf(-w1v));
            sA[w][1] = 1.f / (1.f + expf(-w2v));
            flagL[w] = (w2v - bv3 < 1e-3f) ? 1 : 0;
        }
    }
    __syncthreads();

    // ---- Phase B: inline exact fp64 recompute for flagged rows (block-uniform)
    for (int r = 0; r < 4; ++r) {
        if (!flagL[r]) continue;
        int rblk = bid * 4 + r;
        int h = rblk & 7; int rr = rblk >> 3; int n = rr & 63; int b = rr >> 6;
        // stage keys row + qm panel (vectorized, qm swizzled by t&7)
        for (int idx = tid; idx < 1024; idx += 256) {
            int s = idx >> 3, e4 = idx & 7;
            *(float4*)&ks_t[s][e4 * 4] =
                *(const float4*)&keys[(((size_t)(b * N_ + n)) * L_ + s) * 256 + h * E_ + e4 * 4];
            int e = idx >> 5, t4 = (idx & 31) * 4;
            float4 v = *(const float4*)&qm[((size_t)b * 256 + h * E_ + e) * L_ + t4];
            float vvj[4] = {v.x, v.y, v.z, v.w};
            #pragma unroll
            for (int j = 0; j < 4; ++j) {
                int t = t4 + j;
                int col = ((((e >> 2) ^ (t & 7)) << 2) | (e & 3));
                qs_t[t][col] = vvj[j];
            }
        }
        __syncthreads();
        int tau = tid & 127, hf = tid >> 7;     // 128 tau x 2 e-halves
        double a0 = 0, a1 = 0, a2 = 0, a3 = 0, a4 = 0, a5 = 0, a6 = 0, a7 = 0;
        for (int s = 0; s < L_; ++s) {
            int t = (s + tau) & 127;
            int x = t & 7;
            #pragma unroll
            for (int g = 0; g < 4; g += 2) {
                int g0 = hf * 4 + g;
                float4 k0 = *(const float4*)&ks_t[s][g0 * 4];
                float4 k1 = *(const float4*)&ks_t[s][g0 * 4 + 4];
                float4 q0 = *(const float4*)&qs_t[t][(g0 ^ x) << 2];
                float4 q1 = *(const float4*)&qs_t[t][((g0 + 1) ^ x) << 2];
                a0 = fma((double)k0.x, (double)q0.x, a0);
                a1 = fma((double)k0.y, (double)q0.y, a1);
                a2 = fma((double)k0.z, (double)q0.z, a2);
                a3 = fma((double)k0.w, (double)q0.w, a3);
                a4 = fma((double)k1.x, (double)q1.x, a4);
                a5 = fma((double)k1.y, (double)q1.y, a5);
                a6 = fma((double)k1.z, (double)q1.z, a6);
                a7 = fma((double)k1.w, (double)q1.w, a7);
            }
        }
        vvL[hf][tau] = ((a0 + a1) + (a2 + a3)) + ((a4 + a5) + (a6 + a7));
        __syncthreads();
        if (tid < 64) {
            float v0 = (float)((vvL[0][lane] + vvL[1][lane]) * (1.0 / 32.0));
            float v1 = (float)((vvL[0][lane + 64] + vvL[1][lane + 64]) * (1.0 / 32.0));
            float bv = v0; int bi = lane;
            if (v1 > v0) { bv = v1; bi = lane + 64; }
            #pragma unroll
            for (int m = 32; m; m >>= 1) {
                float ov = __shfl_xor(bv, m, 64);
                int   oi = __shfl_xor(bi, m, 64);
                if (ov > bv || (ov == bv && oi < bi)) { bv = ov; bi = oi; }
            }
            int i1 = bi; float w1v = bv;
            float c0 = (lane == i1) ? -INFINITY : v0;
            float c1 = (lane + 64 == i1) ? -INFINITY : v1;
            float bv2 = c0; int bi2 = lane;
            if (c1 > c0) { bv2 = c1; bi2 = lane + 64; }
            #pragma unroll
            for (int m = 32; m; m >>= 1) {
                float ov = __shfl_xor(bv2, m, 64);
                int   oi = __shfl_xor(bi2, m, 64);
                if (ov > bv2 || (ov == bv2 && oi < bi2)) { bv2 = ov; bi2 = oi; }
            }
            if (lane == 0) {
                dA[r][0] = i1; dA[r][1] = bi2;
                sA[r][0] = 1.f / (1.f + expf(-w1v));
                sA[r][1] = 1.f / (1.f + expf(-bv2));
            }
        }
        __syncthreads();
    }

    if (tid < 8) {
        int rw = tid >> 1, i = tid & 1;
        int row = bid * 4 + rw;
        didx[row * 2 + i] = dA[rw][i];
        sig[row * 2 + i]  = sA[rw][i];
    }
}

// stable argsort over N=64 (didx/sig already final) + emit the per-(blk,i)
// gather table for k_out: gi={pq1,pq2,d1rel,d2rel}, gf={s1,s2,si,di}.
__global__ __launch_bounds__(128) void k_sort(const int* __restrict__ didx,
                                              const float* __restrict__ sig,
                                              int4* __restrict__ gparam_i,
                                              f32x4* __restrict__ gparam_f) {
    int bh = blockIdx.x;                // b*8+h
    int b = bh >> 3, h = bh & 7;
    int tid = threadIdx.x; int i = tid >> 6; int n = tid & 63;
    __shared__ int ds[2][64];
    __shared__ int pm[2][64];
    __shared__ int dival[2][64];
    __shared__ float sigval[2][64];
    {
        int row = (b * 64 + n) * 8 + h;
        int dv = didx[row * 2 + i];
        dival[i][n] = dv;
        sigval[i][n] = sig[row * 2 + i];
        ds[i][n] = 128 - dv;
    }
    __syncthreads();

    int d = ds[i][n];
    int rank = 0;
    for (int m = 0; m < 64; ++m) {
        int dm = ds[i][m];
        rank += (dm < d || (dm == d && m < n)) ? 1 : 0;
    }
    pm[i][rank] = n;
    __syncthreads();
    int p1v = (rank >= 1) ? pm[i][rank - 1] : -1;
    int p2v = (rank >= 2) ? pm[i][rank - 2] : -1;

    int din = dival[i][n];
    int pq1 = (p1v >= 0) ? p1v : n;
    int pq2 = (p2v >= 0) ? p2v : n;
    int d1 = (p1v >= 0) ? ((din - dival[i][p1v]) & 127) : 0;
    int d2 = (p2v >= 0) ? ((din - dival[i][p2v]) & 127) : 0;
    float s1 = (p1v >= 0) ? sigval[i][p1v] : 0.f;
    float s2 = (p2v >= 0) ? sigval[i][p2v] : 0.f;
    int blko = (b * 64 + n) * 8 + h;
    gparam_i[blko * 2 + i] = make_int4(pq1, pq2, d1, d2);
    gparam_f[blko * 2 + i] = (f32x4){s1, s2, sigval[i][n], (float)din};
}

// final gather v7: f16 weight/bias table, nt output stores, XCD-grouped bids,
// precomputed gather table, 1 t per thread.
__global__ __launch_bounds__(256, 3) void k_out(const float* __restrict__ values,
                                                const _Float16* __restrict__ wTh,
                                                const _Float16* __restrict__ bTh,
                                                const int4* __restrict__ gparam_i,
                                                const f32x4* __restrict__ gparam_f,
                                                float* __restrict__ out) {
    int bid = blockIdx.x;
    int h = bid & 7;
    int q = (bid >> 3) & 3;
    int n = (bid >> 5) & 63;
    int b = bid >> 11;
    int blk = (b * 64 + n) * 8 + h;
    int tid = threadIdx.x; int e4 = tid & 7; int tq = tid >> 3;  // 0..31
    int t = q * 32 + tq;

    int4  gi0 = gparam_i[blk * 2 + 0];
    int4  gi1 = gparam_i[blk * 2 + 1];
    f32x4 gf0 = gparam_f[blk * 2 + 0];
    f32x4 gf1 = gparam_f[blk * 2 + 1];
    int di0 = (int)gf0.w, di1 = (int)gf1.w;

    const f32x4* v4 = (const f32x4*)values;
    const f16x4* w4 = (const f16x4*)wTh;
    const f16x4* b4 = (const f16x4*)bTh;
    f32x4* o4 = (f32x4*)out;
    const size_t base = ((size_t)b * N_) * L_ * 64 + h * 8 + e4;

    f32x4 vs  = v4[base + ((size_t)n * L_ + t) * 64];
    f32x4 va1 = v4[base + ((size_t)gi0.x * L_ + ((t + gi0.z) & 127)) * 64];
    f32x4 va2 = v4[base + ((size_t)gi0.y * L_ + ((t + gi0.w) & 127)) * 64];
    f32x4 vb1 = v4[base + ((size_t)gi1.x * L_ + ((t + gi1.z) & 127)) * 64];
    f32x4 vb2 = v4[base + ((size_t)gi1.y * L_ + ((t + gi1.w) & 127)) * 64];
    int wo0 = ((t + di0) & 127) * 8 + e4;
    int wo1 = ((t + di1) & 127) * 8 + e4;
    f32x4 bb0 = __builtin_convertvector(b4[wo0], f32x4);
    f32x4 w0a = __builtin_convertvector(w4[wo0], f32x4);
    f32x4 w1a = __builtin_convertvector(w4[1024 + wo0], f32x4);
    f32x4 w2a = __builtin_convertvector(w4[2048 + wo0], f32x4);
    f32x4 bb1 = __builtin_convertvector(b4[wo1], f32x4);
    f32x4 w0b = __builtin_convertvector(w4[wo1], f32x4);
    f32x4 w1b = __builtin_convertvector(w4[1024 + wo1], f32x4);
    f32x4 w2b = __builtin_convertvector(w4[2048 + wo1], f32x4);

    f32x4 acc = bb0 + bb1;
    acc += w2a * (gf0.z * vs);
    acc += w1a * (gf0.x * va1);
    acc += w0a * (gf0.y * va2);
    acc += w2b * (gf1.z * vs);
    acc += w1b * (gf1.x * vb1);
    acc += w0b * (gf1.y * vb2);
    acc *= 0.5f;
    __builtin_nontemporal_store(acc, &o4[base + ((size_t)n * L_ + t) * 64]);
}

extern "C" void kernel_launch(void* const* d_in, const int* in_sizes, int n_in,
                              void* d_out, int out_size, void* d_ws, size_t ws_size,
                              hipStream_t stream) {
    const float* queries = (const float*)d_in[0];
    const float* keys    = (const float*)d_in[1];
    const float* values  = (const float*)d_in[2];
    const float* w_cf = (const float*)d_in[4];
    const float* b_cf = (const float*)d_in[5];
    float* out = (float*)d_out;

    float* ws    = (float*)d_ws;
    float*    qm  = ws;                       // 131072 f
    _Float16* wTh = (_Float16*)(qm + 131072); // 12288 h (24 KB)
    _Float16* bTh = wTh + 12288;              // 4096 h (8 KB)
    float*  sigp  = (float*)(bTh + 4096);     // 4096 f
    int*   didxp = (int*)(sigp + 4096);       // 4096 i
    int4*  gpi   = (int4*)(didxp + 4096);     // 4096 int4  = 64 KB
    f32x4* gpf   = (f32x4*)(gpi + 4096);      // 4096 f32x4 = 64 KB

    // 8 MB of corr partials live in d_out (fully overwritten by k_out)
    float* part = (float*)d_out;

    k_qmean <<<512,  256, 0, stream>>>(queries, qm, w_cf, b_cf, wTh, bTh);
    k_corr  <<<256,  512, 0, stream>>>(keys, qm, part);
    k_topk  <<<512,  256, 0, stream>>>(part, keys, qm, didxp, sigp);
    k_sort  <<<32,   128, 0, stream>>>(didxp, sigp, gpi, gpf);
    k_out   <<<8192, 256, 0, stream>>>(values, wTh, bTh, gpi, gpf, out);
}

// Round 16
// 74.951 us; speedup vs baseline: 1.3423x; 1.3423x over previous
//
#include <hip/hip_runtime.h>
#include <math.h>

#define B_ 4
#define N_ 64
#define L_ 128
#define H_ 8
#define E_ 32
#define SC_ 8

typedef __attribute__((ext_vector_type(8))) short short8;
typedef __attribute__((ext_vector_type(4))) float f32x4;
typedef __attribute__((ext_vector_type(4))) _Float16 f16x4;

__device__ __forceinline__ unsigned short f2bf(float x) {
    union { float f; unsigned u; } c; c.f = x;
    unsigned r = (c.u + 0x7fffu + ((c.u >> 16) & 1u)) >> 16;
    return (unsigned short)r;
}
__device__ __forceinline__ float bf2f(unsigned short h) {
    union { unsigned u; float f; } c; c.u = ((unsigned)h) << 16;
    return c.f;
}

// qm[b][h][e][t] = mean over n of queries[b,n,t,h,e] (fp64, float4 + LDS reduce).
// Blocks 0..15 also transpose w/b into an f16 table; block 16 zeroes wcnt.
__global__ __launch_bounds__(256) void k_qmean(const float* __restrict__ q,
                                               float* __restrict__ qm,
                                               const float* __restrict__ w,
                                               const float* __restrict__ bias,
                                               _Float16* __restrict__ wTh,
                                               _Float16* __restrict__ bTh,
                                               int* __restrict__ wcnt) {
    int blk = blockIdx.x;               // b*128 + t
    int b = blk >> 7, t = blk & 127;
    int tid = threadIdx.x;
    int c4 = tid & 63;
    int nq = tid >> 6;
    __shared__ double red[4][256];
    const f32x4* p = (const f32x4*)(q + (((size_t)(b * N_)) * L_ + t) * 256);
    double s0 = 0, s1 = 0, s2 = 0, s3 = 0;
    #pragma unroll 4
    for (int n = nq * 16; n < nq * 16 + 16; ++n) {
        f32x4 v = p[(size_t)n * 8192 + c4];
        s0 += (double)v.x; s1 += (double)v.y; s2 += (double)v.z; s3 += (double)v.w;
    }
    red[nq][c4 * 4 + 0] = s0;
    red[nq][c4 * 4 + 1] = s1;
    red[nq][c4 * 4 + 2] = s2;
    red[nq][c4 * 4 + 3] = s3;
    __syncthreads();
    int c = tid;
    double s = red[0][c] + red[1][c] + red[2][c] + red[3][c];
    qm[((size_t)b * 256 + c) * L_ + t] = (float)(s * (1.0 / 64.0));

    if (blk < 16) {
        int k = blk * 256 + tid;        // 4096 = lp*32+e
        int e = k & 31, lp = k >> 5;
        int cc = e * L_ + lp;
        wTh[k]        = (_Float16)w[cc * 3 + 0];
        wTh[4096 + k] = (_Float16)w[cc * 3 + 1];
        wTh[8192 + k] = (_Float16)w[cc * 3 + 2];
        bTh[k]        = (_Float16)bias[cc];
    }
    if (blk == 16 && tid == 0) *wcnt = 0;
}

// MFMA corr: part[sc][b][n][h][tau] = sum_{s in chunk, e} keys[b,n,s,h,e]*qm[b,h,e,(s+tau)%128]
__global__ __launch_bounds__(512) void k_corr(const float* __restrict__ keys,
                                              const float* __restrict__ qm,
                                              float* __restrict__ part) {
    int blk = blockIdx.x;
    int sc = blk & 7; int bh = blk >> 3; int h = bh & 7; int b = bh >> 3;
    __shared__ unsigned short Ahi[4][64][40];
    __shared__ unsigned short Alo[4][64][40];
    __shared__ unsigned short Qhi[128][40];
    __shared__ unsigned short Qlo[128][40];
    int tid = threadIdx.x;
    int lane = tid & 63, w = tid >> 6;
    int mg = w & 1, ng = w >> 1;

    {
        int e = tid >> 4; int tq = (tid & 15) * 4;
        const float* qp = qm + ((size_t)b * 256 + h * 32 + e) * 128;
        #pragma unroll
        for (int hf = 0; hf < 2; ++hf) {
            int t0 = tq + hf * 64;
            float4 v = *(const float4*)(qp + t0);
            float vv[4] = {v.x, v.y, v.z, v.w};
            #pragma unroll
            for (int j = 0; j < 4; ++j) {
                unsigned short hi = f2bf(vv[j]);
                Qhi[t0 + j][e] = hi;
                Qlo[t0 + j][e] = f2bf(vv[j] - bf2f(hi));
            }
        }
    }
    int sn = tid >> 3; int se = (tid & 7) * 4;
    const float* kbase = keys + ((size_t)(b * N_ + sn) * L_) * 256 + h * 32 + se;
    #pragma unroll
    for (int p = 0; p < 2; ++p) {
        float4 v = *(const float4*)(kbase + (size_t)(sc * 16 + p) * 256);
        float vv[4] = {v.x, v.y, v.z, v.w};
        ushort4 h4, l4;
        unsigned short* hp = (unsigned short*)&h4;
        unsigned short* lp = (unsigned short*)&l4;
        #pragma unroll
        for (int j = 0; j < 4; ++j) {
            hp[j] = f2bf(vv[j]);
            lp[j] = f2bf(vv[j] - bf2f(hp[j]));
        }
        *(ushort4*)&Ahi[p][sn][se] = h4;
        *(ushort4*)&Alo[p][sn][se] = l4;
    }
    __syncthreads();

    f32x4 acc[2][2];
    #pragma unroll
    for (int i = 0; i < 2; ++i)
        #pragma unroll
        for (int j = 0; j < 2; ++j)
            acc[i][j] = (f32x4){0.f, 0.f, 0.f, 0.f};

    int eb = (lane >> 4) * 8;
    int rA0 = (mg * 2) * 16 + (lane & 15);
    int rA1 = rA0 + 16;
    int tau0 = (ng * 2) * 16 + (lane & 15);
    int tau1 = tau0 + 16;

    for (int it = 0; it < 8; ++it) {
        float4 stg0, stg1;
        if (it < 7) {
            stg0 = *(const float4*)(kbase + (size_t)(sc * 16 + 2 * it + 2) * 256);
            stg1 = *(const float4*)(kbase + (size_t)(sc * 16 + 2 * it + 3) * 256);
        }
        #pragma unroll
        for (int sp = 0; sp < 2; ++sp) {
            int p = 2 * it + sp;
            int slot = p & 3;
            int s = sc * 16 + p;
            short8 ah0 = *(const short8*)&Ahi[slot][rA0][eb];
            short8 ah1 = *(const short8*)&Ahi[slot][rA1][eb];
            short8 al0 = *(const short8*)&Alo[slot][rA0][eb];
            short8 al1 = *(const short8*)&Alo[slot][rA1][eb];
            int t0 = (s + tau0) & 127;
            int t1 = (s + tau1) & 127;
            short8 bh0 = *(const short8*)&Qhi[t0][eb];
            short8 bh1 = *(const short8*)&Qhi[t1][eb];
            short8 bl0 = *(const short8*)&Qlo[t0][eb];
            short8 bl1 = *(const short8*)&Qlo[t1][eb];
            acc[0][0] = __builtin_amdgcn_mfma_f32_16x16x32_bf16(ah0, bh0, acc[0][0], 0, 0, 0);
            acc[0][1] = __builtin_amdgcn_mfma_f32_16x16x32_bf16(ah0, bh1, acc[0][1], 0, 0, 0);
            acc[1][0] = __builtin_amdgcn_mfma_f32_16x16x32_bf16(ah1, bh0, acc[1][0], 0, 0, 0);
            acc[1][1] = __builtin_amdgcn_mfma_f32_16x16x32_bf16(ah1, bh1, acc[1][1], 0, 0, 0);
            acc[0][0] = __builtin_amdgcn_mfma_f32_16x16x32_bf16(ah0, bl0, acc[0][0], 0, 0, 0);
            acc[0][1] = __builtin_amdgcn_mfma_f32_16x16x32_bf16(ah0, bl1, acc[0][1], 0, 0, 0);
            acc[1][0] = __builtin_amdgcn_mfma_f32_16x16x32_bf16(ah1, bl0, acc[1][0], 0, 0, 0);
            acc[1][1] = __builtin_amdgcn_mfma_f32_16x16x32_bf16(ah1, bl1, acc[1][1], 0, 0, 0);
            acc[0][0] = __builtin_amdgcn_mfma_f32_16x16x32_bf16(al0, bh0, acc[0][0], 0, 0, 0);
            acc[0][1] = __builtin_amdgcn_mfma_f32_16x16x32_bf16(al0, bh1, acc[0][1], 0, 0, 0);
            acc[1][0] = __builtin_amdgcn_mfma_f32_16x16x32_bf16(al1, bh0, acc[1][0], 0, 0, 0);
            acc[1][1] = __builtin_amdgcn_mfma_f32_16x16x32_bf16(al1, bh1, acc[1][1], 0, 0, 0);
        }
        if (it < 7) {
            #pragma unroll
            for (int sp = 0; sp < 2; ++sp) {
                int p = 2 * it + 2 + sp;
                int slot = p & 3;
                float4 v = sp ? stg1 : stg0;
                float vv[4] = {v.x, v.y, v.z, v.w};
                ushort4 h4, l4;
                unsigned short* hp = (unsigned short*)&h4;
                unsigned short* lp = (unsigned short*)&l4;
                #pragma unroll
                for (int j = 0; j < 4; ++j) {
                    hp[j] = f2bf(vv[j]);
                    lp[j] = f2bf(vv[j] - bf2f(hp[j]));
                }
                *(ushort4*)&Ahi[slot][sn][se] = h4;
                *(ushort4*)&Alo[slot][sn][se] = l4;
            }
        }
        __syncthreads();
    }

    #pragma unroll
    for (int i = 0; i < 2; ++i) {
        int mt = mg * 2 + i;
        #pragma unroll
        for (int j = 0; j < 2; ++j) {
            int nt = ng * 2 + j;
            int tau = nt * 16 + (lane & 15);
            #pragma unroll
            for (int r = 0; r < 4; ++r) {
                int n = mt * 16 + (lane >> 4) * 4 + r;
                part[((((size_t)sc * B_ + b) * N_ + n) * H_ + h) * L_ + tau] = acc[i][j][r];
            }
        }
    }
}

// top-2 over tau per (b,n,h) + near-tie flag; flagged rows appended to worklist.
__global__ __launch_bounds__(256) void k_topk(const float* __restrict__ part,
                                              int* __restrict__ didx,
                                              float* __restrict__ sig,
                                              int* __restrict__ flags,
                                              int* __restrict__ wlist,
                                              int* __restrict__ wcnt) {
    int blk = blockIdx.x * 4 + (threadIdx.x >> 6);  // (b*64+n)*8+h
    int lane = threadIdx.x & 63;
    size_t rb = (size_t)blk * L_;
    const size_t stride = (size_t)B_ * N_ * H_ * L_;
    double s0 = 0.0, s1 = 0.0;
    for (int sc = 0; sc < SC_; ++sc) {
        s0 += (double)part[sc * stride + rb + lane];
        s1 += (double)part[sc * stride + rb + lane + 64];
    }
    float v0 = (float)(s0 * (1.0 / 32.0));
    float v1 = (float)(s1 * (1.0 / 32.0));

    float bv = v0; int bi = lane;
    if (v1 > v0) { bv = v1; bi = lane + 64; }
    #pragma unroll
    for (int m = 32; m; m >>= 1) {
        float ov = __shfl_xor(bv, m, 64);
        int   oi = __shfl_xor(bi, m, 64);
        if (ov > bv || (ov == bv && oi < bi)) { bv = ov; bi = oi; }
    }
    int i1 = bi; float w1v = bv;

    float c0 = (lane == i1) ? -INFINITY : v0;
    float c1 = (lane + 64 == i1) ? -INFINITY : v1;
    float bv2 = c0; int bi2 = lane;
    if (c1 > c0) { bv2 = c1; bi2 = lane + 64; }
    #pragma unroll
    for (int m = 32; m; m >>= 1) {
        float ov = __shfl_xor(bv2, m, 64);
        int   oi = __shfl_xor(bi2, m, 64);
        if (ov > bv2 || (ov == bv2 && oi < bi2)) { bv2 = ov; bi2 = oi; }
    }
    int i2 = bi2; float w2v = bv2;

    float d0 = (lane == i1 || lane == i2) ? -INFINITY : v0;
    float d1 = (lane + 64 == i1 || lane + 64 == i2) ? -INFINITY : v1;
    float bv3 = fmaxf(d0, d1);
    #pragma unroll
    for (int m = 32; m; m >>= 1) bv3 = fmaxf(bv3, __shfl_xor(bv3, m, 64));

    if (lane == 0) {
        didx[blk * 2 + 0] = i1;
        didx[blk * 2 + 1] = i2;
        sig[blk * 2 + 0] = 1.f / (1.f + expf(-w1v));
        sig[blk * 2 + 1] = 1.f / (1.f + expf(-w2v));
        int fl = (w2v - bv3 < 1e-3f) ? 1 : 0;
        flags[blk] = fl;
        if (fl) { int s = atomicAdd(wcnt, 1); wlist[s] = blk; }
    }
}

// fp64 recompute of worklisted rows, tau-split 8-way; grid-stride over cnt*8 items.
__global__ __launch_bounds__(256) void k_fixup(const float* __restrict__ keys,
                                               const float* __restrict__ qm,
                                               const int* __restrict__ wlist,
                                               const int* __restrict__ wcnt,
                                               double* __restrict__ vvg) {
    int cnt = *wcnt;
    __shared__ float ks_t[L_][E_];
    __shared__ float qs_t[L_][E_];
    __shared__ double red[16][17];
    int tid = threadIdx.x;
    for (int wi = blockIdx.x; wi < cnt * 8; wi += gridDim.x) {
        int row = wlist[wi >> 3]; int tg = wi & 7;
        int h = row & 7; int r = row >> 3; int n = r & 63; int b = r >> 6;
        __syncthreads();                // protect LDS reuse across loop iterations
        for (int idx = tid; idx < 1024; idx += 256) {
            int s = idx >> 3, e4 = idx & 7;
            *(float4*)&ks_t[s][e4 * 4] =
                *(const float4*)&keys[(((size_t)(b * N_ + n)) * L_ + s) * 256 + h * E_ + e4 * 4];
            int e = idx >> 5, t4 = (idx & 31) * 4;
            float4 v = *(const float4*)&qm[((size_t)b * 256 + h * E_ + e) * L_ + t4];
            float vvj[4] = {v.x, v.y, v.z, v.w};
            #pragma unroll
            for (int j = 0; j < 4; ++j) {
                int t = t4 + j;
                int col = ((((e >> 2) ^ (t & 7)) << 2) | (e & 3));
                qs_t[t][col] = vvj[j];
            }
        }
        __syncthreads();
        int tau = tg * 16 + (tid & 15);
        int g = tid >> 4;
        double a0 = 0, a1 = 0, a2 = 0, a3 = 0, a4 = 0, a5 = 0, a6 = 0, a7 = 0;
        #pragma unroll 2
        for (int s = g * 8; s < g * 8 + 8; ++s) {
            int t = (s + tau) & 127;
            int x = t & 7;
            #pragma unroll
            for (int e4 = 0; e4 < 8; e4 += 2) {
                float4 k0 = *(const float4*)&ks_t[s][e4 * 4];
                float4 k1 = *(const float4*)&ks_t[s][e4 * 4 + 4];
                float4 q0 = *(const float4*)&qs_t[t][(e4 ^ x) << 2];
                float4 q1 = *(const float4*)&qs_t[t][((e4 + 1) ^ x) << 2];
                a0 = fma((double)k0.x, (double)q0.x, a0);
                a1 = fma((double)k0.y, (double)q0.y, a1);
                a2 = fma((double)k0.z, (double)q0.z, a2);
                a3 = fma((double)k0.w, (double)q0.w, a3);
                a4 = fma((double)k1.x, (double)q1.x, a4);
                a5 = fma((double)k1.y, (double)q1.y, a5);
                a6 = fma((double)k1.z, (double)q1.z, a6);
                a7 = fma((double)k1.w, (double)q1.w, a7);
            }
        }
        red[g][tid & 15] = ((a0 + a1) + (a2 + a3)) + ((a4 + a5) + (a6 + a7));
        __syncthreads();
        if (tid < 16) {
            double s = 0;
            #pragma unroll
            for (int gg = 0; gg < 16; ++gg) s += red[gg][tid];
            vvg[(size_t)row * L_ + tg * 16 + tid] = s;
        }
    }
}

// stable argsort over N=64 (flag-override via vvg, all state in LDS) + emit the
// per-(blk,i) gather table for k_out: gi={pq1,pq2,d1rel,d2rel}, gf={s1,s2,si,di}.
__global__ __launch_bounds__(128) void k_sort(const int* __restrict__ didx,
                                              const float* __restrict__ sig,
                                              const int* __restrict__ flags,
                                              const double* __restrict__ vvg,
                                              int4* __restrict__ gparam_i,
                                              f32x4* __restrict__ gparam_f) {
    int bh = blockIdx.x;                // b*8+h
    int b = bh >> 3, h = bh & 7;
    int tid = threadIdx.x; int i = tid >> 6; int n = tid & 63;
    __shared__ int ds[2][64];
    __shared__ int pm[2][64];
    __shared__ int dival[2][64];
    __shared__ float sigval[2][64];
    {
        int row = (b * 64 + n) * 8 + h;
        int dv = didx[row * 2 + i];
        dival[i][n] = dv;
        sigval[i][n] = sig[row * 2 + i];
        ds[i][n] = 128 - dv;
    }
    __syncthreads();

    if (tid < 64) {
        int lane = tid;
        int myflag = flags[(b * 64 + lane) * 8 + h];
        unsigned long long msk = __ballot(myflag != 0);
        while (msk) {
            int nn = __ffsll((long long)msk) - 1; msk &= msk - 1;
            int row = (b * 64 + nn) * 8 + h;
            float v0 = (float)(vvg[(size_t)row * L_ + lane] * (1.0 / 32.0));
            float v1 = (float)(vvg[(size_t)row * L_ + lane + 64] * (1.0 / 32.0));
            float bv = v0; int bi = lane;
            if (v1 > v0) { bv = v1; bi = lane + 64; }
            #pragma unroll
            for (int m = 32; m; m >>= 1) {
                float ov = __shfl_xor(bv, m, 64);
                int   oi = __shfl_xor(bi, m, 64);
                if (ov > bv || (ov == bv && oi < bi)) { bv = ov; bi = oi; }
            }
            int i1 = bi; float w1v = bv;
            float c0 = (lane == i1) ? -INFINITY : v0;
            float c1 = (lane + 64 == i1) ? -INFINITY : v1;
            float bv2 = c0; int bi2 = lane;
            if (c1 > c0) { bv2 = c1; bi2 = lane + 64; }
            #pragma unroll
            for (int m = 32; m; m >>= 1) {
                float ov = __shfl_xor(bv2, m, 64);
                int   oi = __shfl_xor(bi2, m, 64);
                if (ov > bv2 || (ov == bv2 && oi < bi2)) { bv2 = ov; bi2 = oi; }
            }
            if (lane == 0) {
                dival[0][nn] = i1;      ds[0][nn] = 128 - i1;
                dival[1][nn] = bi2;     ds[1][nn] = 128 - bi2;
                sigval[0][nn] = 1.f / (1.f + expf(-w1v));
                sigval[1][nn] = 1.f / (1.f + expf(-bv2));
            }
        }
    }
    __syncthreads();

    int d = ds[i][n];
    int rank = 0;
    for (int m = 0; m < 64; ++m) {
        int dm = ds[i][m];
        rank += (dm < d || (dm == d && m < n)) ? 1 : 0;
    }
    pm[i][rank] = n;
    __syncthreads();
    int p1v = (rank >= 1) ? pm[i][rank - 1] : -1;
    int p2v = (rank >= 2) ? pm[i][rank - 2] : -1;

    int din = dival[i][n];
    int pq1 = (p1v >= 0) ? p1v : n;
    int pq2 = (p2v >= 0) ? p2v : n;
    int d1 = (p1v >= 0) ? ((din - dival[i][p1v]) & 127) : 0;
    int d2 = (p2v >= 0) ? ((din - dival[i][p2v]) & 127) : 0;
    float s1 = (p1v >= 0) ? sigval[i][p1v] : 0.f;
    float s2 = (p2v >= 0) ? sigval[i][p2v] : 0.f;
    int blko = (b * 64 + n) * 8 + h;
    gparam_i[blko * 2 + i] = make_int4(pq1, pq2, d1, d2);
    gparam_f[blko * 2 + i] = (f32x4){s1, s2, sigval[i][n], (float)din};
}

// final gather v7: f16 weight/bias table (halves the dominant L2 stream), nt
// output stores, XCD-grouped bids, precomputed gather table, 1 t per thread.
__global__ __launch_bounds__(256, 3) void k_out(const float* __restrict__ values,
                                                const _Float16* __restrict__ wTh,
                                                const _Float16* __restrict__ bTh,
                                                const int4* __restrict__ gparam_i,
                                                const f32x4* __restrict__ gparam_f,
                                                float* __restrict__ out) {
    int bid = blockIdx.x;
    int h = bid & 7;
    int q = (bid >> 3) & 3;
    int n = (bid >> 5) & 63;
    int b = bid >> 11;
    int blk = (b * 64 + n) * 8 + h;
    int tid = threadIdx.x; int e4 = tid & 7; int tq = tid >> 3;  // 0..31
    int t = q * 32 + tq;

    int4  gi0 = gparam_i[blk * 2 + 0];
    int4  gi1 = gparam_i[blk * 2 + 1];
    f32x4 gf0 = gparam_f[blk * 2 + 0];
    f32x4 gf1 = gparam_f[blk * 2 + 1];
    int di0 = (int)gf0.w, di1 = (int)gf1.w;

    const f32x4* v4 = (const f32x4*)values;
    const f16x4* w4 = (const f16x4*)wTh;
    const f16x4* b4 = (const f16x4*)bTh;
    f32x4* o4 = (f32x4*)out;
    const size_t base = ((size_t)b * N_) * L_ * 64 + h * 8 + e4;

    f32x4 vs  = v4[base + ((size_t)n * L_ + t) * 64];
    f32x4 va1 = v4[base + ((size_t)gi0.x * L_ + ((t + gi0.z) & 127)) * 64];
    f32x4 va2 = v4[base + ((size_t)gi0.y * L_ + ((t + gi0.w) & 127)) * 64];
    f32x4 vb1 = v4[base + ((size_t)gi1.x * L_ + ((t + gi1.z) & 127)) * 64];
    f32x4 vb2 = v4[base + ((size_t)gi1.y * L_ + ((t + gi1.w) & 127)) * 64];
    int wo0 = ((t + di0) & 127) * 8 + e4;
    int wo1 = ((t + di1) & 127) * 8 + e4;
    f32x4 bb0 = __builtin_convertvector(b4[wo0], f32x4);
    f32x4 w0a = __builtin_convertvector(w4[wo0], f32x4);
    f32x4 w1a = __builtin_convertvector(w4[1024 + wo0], f32x4);
    f32x4 w2a = __builtin_convertvector(w4[2048 + wo0], f32x4);
    f32x4 bb1 = __builtin_convertvector(b4[wo1], f32x4);
    f32x4 w0b = __builtin_convertvector(w4[wo1], f32x4);
    f32x4 w1b = __builtin_convertvector(w4[1024 + wo1], f32x4);
    f32x4 w2b = __builtin_convertvector(w4[2048 + wo1], f32x4);

    f32x4 acc = bb0 + bb1;
    acc += w2a * (gf0.z * vs);
    acc += w1a * (gf0.x * va1);
    acc += w0a * (gf0.y * va2);
    acc += w2b * (gf1.z * vs);
    acc += w1b * (gf1.x * vb1);
    acc += w0b * (gf1.y * vb2);
    acc *= 0.5f;
    __builtin_nontemporal_store(acc, &o4[base + ((size_t)n * L_ + t) * 64]);
}

extern "C" void kernel_launch(void* const* d_in, const int* in_sizes, int n_in,
                              void* d_out, int out_size, void* d_ws, size_t ws_size,
                              hipStream_t stream) {
    const float* queries = (const float*)d_in[0];
    const float* keys    = (const float*)d_in[1];
    const float* values  = (const float*)d_in[2];
    const float* w_cf = (const float*)d_in[4];
    const float* b_cf = (const float*)d_in[5];
    float* out = (float*)d_out;

    float* ws    = (float*)d_ws;
    float*    qm  = ws;                       // 131072 f
    _Float16* wTh = (_Float16*)(qm + 131072); // 12288 h (24 KB)
    _Float16* bTh = wTh + 12288;              // 4096 h (8 KB)
    float*  sigp  = (float*)(bTh + 4096);     // 4096 f
    int*   didxp = (int*)(sigp + 4096);       // 4096 i
    int*   flags = didxp + 4096;              // 2048 i
    int*   wlist = flags + 2048;              // 2048 i
    int*   wcnt  = wlist + 2048;              // 4 i (padded)
    double* vvg  = (double*)(wcnt + 4);       // 2048*128 fp64 = 2 MB
    int4*  gpi   = (int4*)(vvg + 2048 * 128); // 4096 int4  = 64 KB
    f32x4* gpf   = (f32x4*)(gpi + 4096);      // 4096 f32x4 = 64 KB

    // 8 MB of corr partials live in d_out (fully overwritten by k_out)
    float* part = (float*)d_out;

    k_qmean <<<512,  256, 0, stream>>>(queries, qm, w_cf, b_cf, wTh, bTh, wcnt);
    k_corr  <<<256,  512, 0, stream>>>(keys, qm, part);
    k_topk  <<<512,  256, 0, stream>>>(part, didxp, sigp, flags, wlist, wcnt);
    k_fixup <<<128,  256, 0, stream>>>(keys, qm, wlist, wcnt, vvg);
    k_sort  <<<32,   128, 0, stream>>>(didxp, sigp, flags, vvg, gpi, gpf);
    k_out   <<<8192, 256, 0, stream>>>(values, wTh, bTh, gpi, gpf, out);
}

// Round 17
// 70.213 us; speedup vs baseline: 1.4329x; 1.0675x over previous
//
#include <hip/hip_runtime.h>
#include <math.h>

#define B_ 4
#define N_ 64
#define L_ 128
#define H_ 8
#define E_ 32
#define SC_ 8

typedef __attribute__((ext_vector_type(8))) short short8;
typedef __attribute__((ext_vector_type(4))) float f32x4;
typedef __attribute__((ext_vector_type(4))) _Float16 f16x4;

__device__ __forceinline__ unsigned short f2bf(float x) {
    union { float f; unsigned u; } c; c.f = x;
    unsigned r = (c.u + 0x7fffu + ((c.u >> 16) & 1u)) >> 16;
    return (unsigned short)r;
}
__device__ __forceinline__ float bf2f(unsigned short h) {
    union { unsigned u; float f; } c; c.u = ((unsigned)h) << 16;
    return c.f;
}

// qm[b][h][e][t] = mean over n of queries[b,n,t,h,e] (fp64, float4 + LDS reduce).
// Blocks 0..15 also transpose w/b into an f16 table; block 16 zeroes wcnt.
__global__ __launch_bounds__(256) void k_qmean(const float* __restrict__ q,
                                               float* __restrict__ qm,
                                               const float* __restrict__ w,
                                               const float* __restrict__ bias,
                                               _Float16* __restrict__ wTh,
                                               _Float16* __restrict__ bTh,
                                               int* __restrict__ wcnt) {
    int blk = blockIdx.x;               // b*128 + t
    int b = blk >> 7, t = blk & 127;
    int tid = threadIdx.x;
    int c4 = tid & 63;
    int nq = tid >> 6;
    __shared__ double red[4][256];
    const f32x4* p = (const f32x4*)(q + (((size_t)(b * N_)) * L_ + t) * 256);
    double s0 = 0, s1 = 0, s2 = 0, s3 = 0;
    #pragma unroll 4
    for (int n = nq * 16; n < nq * 16 + 16; ++n) {
        f32x4 v = p[(size_t)n * 8192 + c4];
        s0 += (double)v.x; s1 += (double)v.y; s2 += (double)v.z; s3 += (double)v.w;
    }
    red[nq][c4 * 4 + 0] = s0;
    red[nq][c4 * 4 + 1] = s1;
    red[nq][c4 * 4 + 2] = s2;
    red[nq][c4 * 4 + 3] = s3;
    __syncthreads();
    int c = tid;
    double s = red[0][c] + red[1][c] + red[2][c] + red[3][c];
    qm[((size_t)b * 256 + c) * L_ + t] = (float)(s * (1.0 / 64.0));

    if (blk < 16) {
        int k = blk * 256 + tid;        // 4096 = lp*32+e
        int e = k & 31, lp = k >> 5;
        int cc = e * L_ + lp;
        wTh[k]        = (_Float16)w[cc * 3 + 0];
        wTh[4096 + k] = (_Float16)w[cc * 3 + 1];
        wTh[8192 + k] = (_Float16)w[cc * 3 + 2];
        bTh[k]        = (_Float16)bias[cc];
    }
    if (blk == 16 && tid == 0) *wcnt = 0;
}

// MFMA corr: part[sc][b][n][h][tau] = sum_{s in chunk, e} keys[b,n,s,h,e]*qm[b,h,e,(s+tau)%128]
__global__ __launch_bounds__(512) void k_corr(const float* __restrict__ keys,
                                              const float* __restrict__ qm,
                                              float* __restrict__ part) {
    int blk = blockIdx.x;
    int sc = blk & 7; int bh = blk >> 3; int h = bh & 7; int b = bh >> 3;
    __shared__ unsigned short Ahi[4][64][40];
    __shared__ unsigned short Alo[4][64][40];
    __shared__ unsigned short Qhi[128][40];
    __shared__ unsigned short Qlo[128][40];
    int tid = threadIdx.x;
    int lane = tid & 63, w = tid >> 6;
    int mg = w & 1, ng = w >> 1;

    {
        int e = tid >> 4; int tq = (tid & 15) * 4;
        const float* qp = qm + ((size_t)b * 256 + h * 32 + e) * 128;
        #pragma unroll
        for (int hf = 0; hf < 2; ++hf) {
            int t0 = tq + hf * 64;
            float4 v = *(const float4*)(qp + t0);
            float vv[4] = {v.x, v.y, v.z, v.w};
            #pragma unroll
            for (int j = 0; j < 4; ++j) {
                unsigned short hi = f2bf(vv[j]);
                Qhi[t0 + j][e] = hi;
                Qlo[t0 + j][e] = f2bf(vv[j] - bf2f(hi));
            }
        }
    }
    int sn = tid >> 3; int se = (tid & 7) * 4;
    const float* kbase = keys + ((size_t)(b * N_ + sn) * L_) * 256 + h * 32 + se;
    #pragma unroll
    for (int p = 0; p < 2; ++p) {
        float4 v = *(const float4*)(kbase + (size_t)(sc * 16 + p) * 256);
        float vv[4] = {v.x, v.y, v.z, v.w};
        ushort4 h4, l4;
        unsigned short* hp = (unsigned short*)&h4;
        unsigned short* lp = (unsigned short*)&l4;
        #pragma unroll
        for (int j = 0; j < 4; ++j) {
            hp[j] = f2bf(vv[j]);
            lp[j] = f2bf(vv[j] - bf2f(hp[j]));
        }
        *(ushort4*)&Ahi[p][sn][se] = h4;
        *(ushort4*)&Alo[p][sn][se] = l4;
    }
    __syncthreads();

    f32x4 acc[2][2];
    #pragma unroll
    for (int i = 0; i < 2; ++i)
        #pragma unroll
        for (int j = 0; j < 2; ++j)
            acc[i][j] = (f32x4){0.f, 0.f, 0.f, 0.f};

    int eb = (lane >> 4) * 8;
    int rA0 = (mg * 2) * 16 + (lane & 15);
    int rA1 = rA0 + 16;
    int tau0 = (ng * 2) * 16 + (lane & 15);
    int tau1 = tau0 + 16;

    for (int it = 0; it < 8; ++it) {
        float4 stg0, stg1;
        if (it < 7) {
            stg0 = *(const float4*)(kbase + (size_t)(sc * 16 + 2 * it + 2) * 256);
            stg1 = *(const float4*)(kbase + (size_t)(sc * 16 + 2 * it + 3) * 256);
        }
        #pragma unroll
        for (int sp = 0; sp < 2; ++sp) {
            int p = 2 * it + sp;
            int slot = p & 3;
            int s = sc * 16 + p;
            short8 ah0 = *(const short8*)&Ahi[slot][rA0][eb];
            short8 ah1 = *(const short8*)&Ahi[slot][rA1][eb];
            short8 al0 = *(const short8*)&Alo[slot][rA0][eb];
            short8 al1 = *(const short8*)&Alo[slot][rA1][eb];
            int t0 = (s + tau0) & 127;
            int t1 = (s + tau1) & 127;
            short8 bh0 = *(const short8*)&Qhi[t0][eb];
            short8 bh1 = *(const short8*)&Qhi[t1][eb];
            short8 bl0 = *(const short8*)&Qlo[t0][eb];
            short8 bl1 = *(const short8*)&Qlo[t1][eb];
            acc[0][0] = __builtin_amdgcn_mfma_f32_16x16x32_bf16(ah0, bh0, acc[0][0], 0, 0, 0);
            acc[0][1] = __builtin_amdgcn_mfma_f32_16x16x32_bf16(ah0, bh1, acc[0][1], 0, 0, 0);
            acc[1][0] = __builtin_amdgcn_mfma_f32_16x16x32_bf16(ah1, bh0, acc[1][0], 0, 0, 0);
            acc[1][1] = __builtin_amdgcn_mfma_f32_16x16x32_bf16(ah1, bh1, acc[1][1], 0, 0, 0);
            acc[0][0] = __builtin_amdgcn_mfma_f32_16x16x32_bf16(ah0, bl0, acc[0][0], 0, 0, 0);
            acc[0][1] = __builtin_amdgcn_mfma_f32_16x16x32_bf16(ah0, bl1, acc[0][1], 0, 0, 0);
            acc[1][0] = __builtin_amdgcn_mfma_f32_16x16x32_bf16(ah1, bl0, acc[1][0], 0, 0, 0);
            acc[1][1] = __builtin_amdgcn_mfma_f32_16x16x32_bf16(ah1, bl1, acc[1][1], 0, 0, 0);
            acc[0][0] = __builtin_amdgcn_mfma_f32_16x16x32_bf16(al0, bh0, acc[0][0], 0, 0, 0);
            acc[0][1] = __builtin_amdgcn_mfma_f32_16x16x32_bf16(al0, bh1, acc[0][1], 0, 0, 0);
            acc[1][0] = __builtin_amdgcn_mfma_f32_16x16x32_bf16(al1, bh0, acc[1][0], 0, 0, 0);
            acc[1][1] = __builtin_amdgcn_mfma_f32_16x16x32_bf16(al1, bh1, acc[1][1], 0, 0, 0);
        }
        if (it < 7) {
            #pragma unroll
            for (int sp = 0; sp < 2; ++sp) {
                int p = 2 * it + 2 + sp;
                int slot = p & 3;
                float4 v = sp ? stg1 : stg0;
                float vv[4] = {v.x, v.y, v.z, v.w};
                ushort4 h4, l4;
                unsigned short* hp = (unsigned short*)&h4;
                unsigned short* lp = (unsigned short*)&l4;
                #pragma unroll
                for (int j = 0; j < 4; ++j) {
                    hp[j] = f2bf(vv[j]);
                    lp[j] = f2bf(vv[j] - bf2f(hp[j]));
                }
                *(ushort4*)&Ahi[slot][sn][se] = h4;
                *(ushort4*)&Alo[slot][sn][se] = l4;
            }
        }
        __syncthreads();
    }

    #pragma unroll
    for (int i = 0; i < 2; ++i) {
        int mt = mg * 2 + i;
        #pragma unroll
        for (int j = 0; j < 2; ++j) {
            int nt = ng * 2 + j;
            int tau = nt * 16 + (lane & 15);
            #pragma unroll
            for (int r = 0; r < 4; ++r) {
                int n = mt * 16 + (lane >> 4) * 4 + r;
                part[((((size_t)sc * B_ + b) * N_ + n) * H_ + h) * L_ + tau] = acc[i][j][r];
            }
        }
    }
}

// top-2 over tau per (b,n,h) + near-tie flag; flagged rows appended to worklist.
__global__ __launch_bounds__(256) void k_topk(const float* __restrict__ part,
                                              int* __restrict__ didx,
                                              float* __restrict__ sig,
                                              int* __restrict__ flags,
                                              int* __restrict__ wlist,
                                              int* __restrict__ wcnt) {
    int blk = blockIdx.x * 4 + (threadIdx.x >> 6);  // (b*64+n)*8+h
    int lane = threadIdx.x & 63;
    size_t rb = (size_t)blk * L_;
    const size_t stride = (size_t)B_ * N_ * H_ * L_;
    double s0 = 0.0, s1 = 0.0;
    for (int sc = 0; sc < SC_; ++sc) {
        s0 += (double)part[sc * stride + rb + lane];
        s1 += (double)part[sc * stride + rb + lane + 64];
    }
    float v0 = (float)(s0 * (1.0 / 32.0));
    float v1 = (float)(s1 * (1.0 / 32.0));

    float bv = v0; int bi = lane;
    if (v1 > v0) { bv = v1; bi = lane + 64; }
    #pragma unroll
    for (int m = 32; m; m >>= 1) {
        float ov = __shfl_xor(bv, m, 64);
        int   oi = __shfl_xor(bi, m, 64);
        if (ov > bv || (ov == bv && oi < bi)) { bv = ov; bi = oi; }
    }
    int i1 = bi; float w1v = bv;

    float c0 = (lane == i1) ? -INFINITY : v0;
    float c1 = (lane + 64 == i1) ? -INFINITY : v1;
    float bv2 = c0; int bi2 = lane;
    if (c1 > c0) { bv2 = c1; bi2 = lane + 64; }
    #pragma unroll
    for (int m = 32; m; m >>= 1) {
        float ov = __shfl_xor(bv2, m, 64);
        int   oi = __shfl_xor(bi2, m, 64);
        if (ov > bv2 || (ov == bv2 && oi < bi2)) { bv2 = ov; bi2 = oi; }
    }
    int i2 = bi2; float w2v = bv2;

    float d0 = (lane == i1 || lane == i2) ? -INFINITY : v0;
    float d1 = (lane + 64 == i1 || lane + 64 == i2) ? -INFINITY : v1;
    float bv3 = fmaxf(d0, d1);
    #pragma unroll
    for (int m = 32; m; m >>= 1) bv3 = fmaxf(bv3, __shfl_xor(bv3, m, 64));

    if (lane == 0) {
        didx[blk * 2 + 0] = i1;
        didx[blk * 2 + 1] = i2;
        sig[blk * 2 + 0] = 1.f / (1.f + expf(-w1v));
        sig[blk * 2 + 1] = 1.f / (1.f + expf(-w2v));
        int fl = (w2v - bv3 < 1e-3f) ? 1 : 0;
        flags[blk] = fl;
        if (fl) { int s = atomicAdd(wcnt, 1); wlist[s] = blk; }
    }
}

// fp64 recompute of worklisted rows, tau-split 8-way; grid-stride over cnt*8 items.
__global__ __launch_bounds__(256) void k_fixup(const float* __restrict__ keys,
                                               const float* __restrict__ qm,
                                               const int* __restrict__ wlist,
                                               const int* __restrict__ wcnt,
                                               double* __restrict__ vvg) {
    int cnt = *wcnt;
    __shared__ float ks_t[L_][E_];
    __shared__ float qs_t[L_][E_];
    __shared__ double red[16][17];
    int tid = threadIdx.x;
    for (int wi = blockIdx.x; wi < cnt * 8; wi += gridDim.x) {
        int row = wlist[wi >> 3]; int tg = wi & 7;
        int h = row & 7; int r = row >> 3; int n = r & 63; int b = r >> 6;
        __syncthreads();                // protect LDS reuse across loop iterations
        for (int idx = tid; idx < 1024; idx += 256) {
            int s = idx >> 3, e4 = idx & 7;
            *(float4*)&ks_t[s][e4 * 4] =
                *(const float4*)&keys[(((size_t)(b * N_ + n)) * L_ + s) * 256 + h * E_ + e4 * 4];
            int e = idx >> 5, t4 = (idx & 31) * 4;
            float4 v = *(const float4*)&qm[((size_t)b * 256 + h * E_ + e) * L_ + t4];
            float vvj[4] = {v.x, v.y, v.z, v.w};
            #pragma unroll
            for (int j = 0; j < 4; ++j) {
                int t = t4 + j;
                int col = ((((e >> 2) ^ (t & 7)) << 2) | (e & 3));
                qs_t[t][col] = vvj[j];
            }
        }
        __syncthreads();
        int tau = tg * 16 + (tid & 15);
        int g = tid >> 4;
        double a0 = 0, a1 = 0, a2 = 0, a3 = 0, a4 = 0, a5 = 0, a6 = 0, a7 = 0;
        #pragma unroll 2
        for (int s = g * 8; s < g * 8 + 8; ++s) {
            int t = (s + tau) & 127;
            int x = t & 7;
            #pragma unroll
            for (int e4 = 0; e4 < 8; e4 += 2) {
                float4 k0 = *(const float4*)&ks_t[s][e4 * 4];
                float4 k1 = *(const float4*)&ks_t[s][e4 * 4 + 4];
                float4 q0 = *(const float4*)&qs_t[t][(e4 ^ x) << 2];
                float4 q1 = *(const float4*)&qs_t[t][((e4 + 1) ^ x) << 2];
                a0 = fma((double)k0.x, (double)q0.x, a0);
                a1 = fma((double)k0.y, (double)q0.y, a1);
                a2 = fma((double)k0.z, (double)q0.z, a2);
                a3 = fma((double)k0.w, (double)q0.w, a3);
                a4 = fma((double)k1.x, (double)q1.x, a4);
                a5 = fma((double)k1.y, (double)q1.y, a5);
                a6 = fma((double)k1.z, (double)q1.z, a6);
                a7 = fma((double)k1.w, (double)q1.w, a7);
            }
        }
        red[g][tid & 15] = ((a0 + a1) + (a2 + a3)) + ((a4 + a5) + (a6 + a7));
        __syncthreads();
        if (tid < 16) {
            double s = 0;
            #pragma unroll
            for (int gg = 0; gg < 16; ++gg) s += red[gg][tid];
            vvg[(size_t)row * L_ + tg * 16 + tid] = s;
        }
    }
}

// stable argsort over N=64 (flag-override via vvg, all state in LDS) + emit the
// per-(blk,i) gather table for k_out: gi={pq1,pq2,d1rel,d2rel}, gf={s1,s2,si,di}.
__global__ __launch_bounds__(128) void k_sort(const int* __restrict__ didx,
                                              const float* __restrict__ sig,
                                              const int* __restrict__ flags,
                                              const double* __restrict__ vvg,
                                              int4* __restrict__ gparam_i,
                                              f32x4* __restrict__ gparam_f) {
    int bh = blockIdx.x;                // b*8+h
    int b = bh >> 3, h = bh & 7;
    int tid = threadIdx.x; int i = tid >> 6; int n = tid & 63;
    __shared__ int ds[2][64];
    __shared__ int pm[2][64];
    __shared__ int dival[2][64];
    __shared__ float sigval[2][64];
    {
        int row = (b * 64 + n) * 8 + h;
        int dv = didx[row * 2 + i];
        dival[i][n] = dv;
        sigval[i][n] = sig[row * 2 + i];
        ds[i][n] = 128 - dv;
    }
    __syncthreads();

    if (tid < 64) {
        int lane = tid;
        int myflag = flags[(b * 64 + lane) * 8 + h];
        unsigned long long msk = __ballot(myflag != 0);
        while (msk) {
            int nn = __ffsll((long long)msk) - 1; msk &= msk - 1;
            int row = (b * 64 + nn) * 8 + h;
            float v0 = (float)(vvg[(size_t)row * L_ + lane] * (1.0 / 32.0));
            float v1 = (float)(vvg[(size_t)row * L_ + lane + 64] * (1.0 / 32.0));
            float bv = v0; int bi = lane;
            if (v1 > v0) { bv = v1; bi = lane + 64; }
            #pragma unroll
            for (int m = 32; m; m >>= 1) {
                float ov = __shfl_xor(bv, m, 64);
                int   oi = __shfl_xor(bi, m, 64);
                if (ov > bv || (ov == bv && oi < bi)) { bv = ov; bi = oi; }
            }
            int i1 = bi; float w1v = bv;
            float c0 = (lane == i1) ? -INFINITY : v0;
            float c1 = (lane + 64 == i1) ? -INFINITY : v1;
            float bv2 = c0; int bi2 = lane;
            if (c1 > c0) { bv2 = c1; bi2 = lane + 64; }
            #pragma unroll
            for (int m = 32; m; m >>= 1) {
                float ov = __shfl_xor(bv2, m, 64);
                int   oi = __shfl_xor(bi2, m, 64);
                if (ov > bv2 || (ov == bv2 && oi < bi2)) { bv2 = ov; bi2 = oi; }
            }
            if (lane == 0) {
                dival[0][nn] = i1;      ds[0][nn] = 128 - i1;
                dival[1][nn] = bi2;     ds[1][nn] = 128 - bi2;
                sigval[0][nn] = 1.f / (1.f + expf(-w1v));
                sigval[1][nn] = 1.f / (1.f + expf(-bv2));
            }
        }
    }
    __syncthreads();

    int d = ds[i][n];
    int rank = 0;
    for (int m = 0; m < 64; ++m) {
        int dm = ds[i][m];
        rank += (dm < d || (dm == d && m < n)) ? 1 : 0;
    }
    pm[i][rank] = n;
    __syncthreads();
    int p1v = (rank >= 1) ? pm[i][rank - 1] : -1;
    int p2v = (rank >= 2) ? pm[i][rank - 2] : -1;

    int din = dival[i][n];
    int pq1 = (p1v >= 0) ? p1v : n;
    int pq2 = (p2v >= 0) ? p2v : n;
    int d1 = (p1v >= 0) ? ((din - dival[i][p1v]) & 127) : 0;
    int d2 = (p2v >= 0) ? ((din - dival[i][p2v]) & 127) : 0;
    float s1 = (p1v >= 0) ? sigval[i][p1v] : 0.f;
    float s2 = (p2v >= 0) ? sigval[i][p2v] : 0.f;
    int blko = (b * 64 + n) * 8 + h;
    gparam_i[blko * 2 + i] = make_int4(pq1, pq2, d1, d2);
    gparam_f[blko * 2 + i] = (f32x4){s1, s2, sigval[i][n], (float)din};
}

// final gather v7: f16 weight/bias table, nt output stores, XCD-grouped bids,
// precomputed gather table, 1 t per thread.
__global__ __launch_bounds__(256, 3) void k_out(const float* __restrict__ values,
                                                const _Float16* __restrict__ wTh,
                                                const _Float16* __restrict__ bTh,
                                                const int4* __restrict__ gparam_i,
                                                const f32x4* __restrict__ gparam_f,
                                                float* __restrict__ out) {
    int bid = blockIdx.x;
    int h = bid & 7;
    int q = (bid >> 3) & 3;
    int n = (bid >> 5) & 63;
    int b = bid >> 11;
    int blk = (b * 64 + n) * 8 + h;
    int tid = threadIdx.x; int e4 = tid & 7; int tq = tid >> 3;  // 0..31
    int t = q * 32 + tq;

    int4  gi0 = gparam_i[blk * 2 + 0];
    int4  gi1 = gparam_i[blk * 2 + 1];
    f32x4 gf0 = gparam_f[blk * 2 + 0];
    f32x4 gf1 = gparam_f[blk * 2 + 1];
    int di0 = (int)gf0.w, di1 = (int)gf1.w;

    const f32x4* v4 = (const f32x4*)values;
    const f16x4* w4 = (const f16x4*)wTh;
    const f16x4* b4 = (const f16x4*)bTh;
    f32x4* o4 = (f32x4*)out;
    const size_t base = ((size_t)b * N_) * L_ * 64 + h * 8 + e4;

    f32x4 vs  = v4[base + ((size_t)n * L_ + t) * 64];
    f32x4 va1 = v4[base + ((size_t)gi0.x * L_ + ((t + gi0.z) & 127)) * 64];
    f32x4 va2 = v4[base + ((size_t)gi0.y * L_ + ((t + gi0.w) & 127)) * 64];
    f32x4 vb1 = v4[base + ((size_t)gi1.x * L_ + ((t + gi1.z) & 127)) * 64];
    f32x4 vb2 = v4[base + ((size_t)gi1.y * L_ + ((t + gi1.w) & 127)) * 64];
    int wo0 = ((t + di0) & 127) * 8 + e4;
    int wo1 = ((t + di1) & 127) * 8 + e4;
    f32x4 bb0 = __builtin_convertvector(b4[wo0], f32x4);
    f32x4 w0a = __builtin_convertvector(w4[wo0], f32x4);
    f32x4 w1a = __builtin_convertvector(w4[1024 + wo0], f32x4);
    f32x4 w2a = __builtin_convertvector(w4[2048 + wo0], f32x4);
    f32x4 bb1 = __builtin_convertvector(b4[wo1], f32x4);
    f32x4 w0b = __builtin_convertvector(w4[wo1], f32x4);
    f32x4 w1b = __builtin_convertvector(w4[1024 + wo1], f32x4);
    f32x4 w2b = __builtin_convertvector(w4[2048 + wo1], f32x4);

    f32x4 acc = bb0 + bb1;
    acc += w2a * (gf0.z * vs);
    acc += w1a * (gf0.x * va1);
    acc += w0a * (gf0.y * va2);
    acc += w2b * (gf1.z * vs);
    acc += w1b * (gf1.x * vb1);
    acc += w0b * (gf1.y * vb2);
    acc *= 0.5f;
    __builtin_nontemporal_store(acc, &o4[base + ((size_t)n * L_ + t) * 64]);
}

extern "C" void kernel_launch(void* const* d_in, const int* in_sizes, int n_in,
                              void* d_out, int out_size, void* d_ws, size_t ws_size,
                              hipStream_t stream) {
    const float* queries = (const float*)d_in[0];
    const float* keys    = (const float*)d_in[1];
    const float* values  = (const float*)d_in[2];
    const float* w_cf = (const float*)d_in[4];
    const float* b_cf = (const float*)d_in[5];
    float* out = (float*)d_out;

    float* ws    = (float*)d_ws;
    float*    qm  = ws;                       // 131072 f
    _Float16* wTh = (_Float16*)(qm + 131072); // 12288 h (24 KB)
    _Float16* bTh = wTh + 12288;              // 4096 h (8 KB)
    float*  sigp  = (float*)(bTh + 4096);     // 4096 f
    int*   didxp = (int*)(sigp + 4096);       // 4096 i
    int*   flags = didxp + 4096;              // 2048 i
    int*   wlist = flags + 2048;              // 2048 i
    int*   wcnt  = wlist + 2048;              // 4 i (padded)
    double* vvg  = (double*)(wcnt + 4);       // 2048*128 fp64 = 2 MB
    int4*  gpi   = (int4*)(vvg + 2048 * 128); // 4096 int4  = 64 KB
    f32x4* gpf   = (f32x4*)(gpi + 4096);      // 4096 f32x4 = 64 KB

    // 8 MB of corr partials live in d_out (fully overwritten by k_out)
    float* part = (float*)d_out;

    k_qmean <<<512,  256, 0, stream>>>(queries, qm, w_cf, b_cf, wTh, bTh, wcnt);
    k_corr  <<<256,  512, 0, stream>>>(keys, qm, part);
    k_topk  <<<512,  256, 0, stream>>>(part, didxp, sigp, flags, wlist, wcnt);
    k_fixup <<<256,  256, 0, stream>>>(keys, qm, wlist, wcnt, vvg);
    k_sort  <<<32,   128, 0, stream>>>(didxp, sigp, flags, vvg, gpi, gpf);
    k_out   <<<8192, 256, 0, stream>>>(values, wTh, bTh, gpi, gpf, out);
}